// Round 1
// baseline (914.433 us; speedup 1.0000x reference)
//
#include <hip/hip_runtime.h>
#include <hip/hip_bf16.h>

#define EPS 1e-5f
#define D4 32  // 128 dims = 32 float4s per row

// Pass 1: per-segment sum and sum-of-squares per feature dim.
// grid = (blocksPerSeg, B), block = 256.
// Thread t: c4 = t&31 (float4 column), rg = t>>5 (row slot, 8 rows/iter).
__global__ __launch_bounds__(256) void pin_stats_kernel(
    const float* __restrict__ x, const int* __restrict__ seqlen,
    float* __restrict__ gsum, float* __restrict__ gsq) {
    const int b = blockIdx.y;
    const int start = seqlen[b];
    const int rows = seqlen[b + 1] - start;
    const int c4 = threadIdx.x & 31;
    const int rg = threadIdx.x >> 5;

    float4 sum = make_float4(0.f, 0.f, 0.f, 0.f);
    float4 sq  = make_float4(0.f, 0.f, 0.f, 0.f);
    const float4* xp = (const float4*)x + (size_t)start * D4;
    const int rstride = gridDim.x * 8;
    for (int r = blockIdx.x * 8 + rg; r < rows; r += rstride) {
        float4 v = xp[(size_t)r * D4 + c4];
        sum.x += v.x; sum.y += v.y; sum.z += v.z; sum.w += v.w;
        sq.x += v.x * v.x; sq.y += v.y * v.y;
        sq.z += v.z * v.z; sq.w += v.w * v.w;
    }

    __shared__ float4 ssum[256];
    __shared__ float4 ssq[256];
    ssum[threadIdx.x] = sum;
    ssq[threadIdx.x]  = sq;
    __syncthreads();

    if (threadIdx.x < 32) {
        float4 ts = ssum[threadIdx.x];
        float4 tq = ssq[threadIdx.x];
        #pragma unroll
        for (int g = 1; g < 8; ++g) {
            float4 a = ssum[g * 32 + threadIdx.x];
            float4 q = ssq[g * 32 + threadIdx.x];
            ts.x += a.x; ts.y += a.y; ts.z += a.z; ts.w += a.w;
            tq.x += q.x; tq.y += q.y; tq.z += q.z; tq.w += q.w;
        }
        float* gs = gsum + b * 128 + threadIdx.x * 4;
        float* gq = gsq  + b * 128 + threadIdx.x * 4;
        atomicAdd(gs + 0, ts.x); atomicAdd(gs + 1, ts.y);
        atomicAdd(gs + 2, ts.z); atomicAdd(gs + 3, ts.w);
        atomicAdd(gq + 0, tq.x); atomicAdd(gq + 1, tq.y);
        atomicAdd(gq + 2, tq.z); atomicAdd(gq + 3, tq.w);
    }
}

// Pass 2: out = x * scale + shift, scale/shift derived from sums.
// grid = (blocksPerSeg, B), block = 256, same thread layout.
__global__ __launch_bounds__(256) void pin_norm_kernel(
    const float* __restrict__ x, const int* __restrict__ seqlen,
    const float* __restrict__ gsum, const float* __restrict__ gsq,
    const float* __restrict__ weight, const float* __restrict__ bias,
    float* __restrict__ out) {
    const int b = blockIdx.y;
    const int start = seqlen[b];
    const int rows = seqlen[b + 1] - start;
    const int c4 = threadIdx.x & 31;
    const int rg = threadIdx.x >> 5;
    const int d = c4 * 4;

    const float denom = fmaxf((float)rows, 1.0f);
    const float inv_n = 1.0f / denom;
    float4 s = *(const float4*)(gsum + b * 128 + d);
    float4 q = *(const float4*)(gsq  + b * 128 + d);
    float4 w = *(const float4*)(weight + d);
    float4 bi = *(const float4*)(bias + d);

    float4 scale, shift;
    {
        float m, v, is;
        m = s.x * inv_n; v = q.x * inv_n - m * m; is = rsqrtf(v + EPS);
        scale.x = w.x * is; shift.x = bi.x - m * scale.x;
        m = s.y * inv_n; v = q.y * inv_n - m * m; is = rsqrtf(v + EPS);
        scale.y = w.y * is; shift.y = bi.y - m * scale.y;
        m = s.z * inv_n; v = q.z * inv_n - m * m; is = rsqrtf(v + EPS);
        scale.z = w.z * is; shift.z = bi.z - m * scale.z;
        m = s.w * inv_n; v = q.w * inv_n - m * m; is = rsqrtf(v + EPS);
        scale.w = w.w * is; shift.w = bi.w - m * scale.w;
    }

    const float4* xp = (const float4*)x + (size_t)start * D4;
    float4* op = (float4*)out + (size_t)start * D4;
    const int rstride = gridDim.x * 8;
    for (int r = blockIdx.x * 8 + rg; r < rows; r += rstride) {
        size_t idx = (size_t)r * D4 + c4;
        float4 v = xp[idx];
        float4 o;
        o.x = v.x * scale.x + shift.x;
        o.y = v.y * scale.y + shift.y;
        o.z = v.z * scale.z + shift.z;
        o.w = v.w * scale.w + shift.w;
        op[idx] = o;
    }
}

extern "C" void kernel_launch(void* const* d_in, const int* in_sizes, int n_in,
                              void* d_out, int out_size, void* d_ws, size_t ws_size,
                              hipStream_t stream) {
    const float* x      = (const float*)d_in[0];
    const int*   seqlen = (const int*)d_in[1];
    const float* weight = (const float*)d_in[2];
    const float* bias   = (const float*)d_in[3];
    float* out = (float*)d_out;

    const int B = in_sizes[1] - 1;            // 16
    float* gsum = (float*)d_ws;               // [B][128]
    float* gsq  = gsum + (size_t)B * 128;     // [B][128]

    // Workspace is poisoned to 0xAA before every launch — zero the accumulators.
    hipMemsetAsync(d_ws, 0, (size_t)B * 128 * 2 * sizeof(float), stream);

    dim3 block(256);
    dim3 grid1(64, B);    // 1024 blocks, ~123 iters each
    pin_stats_kernel<<<grid1, block, 0, stream>>>(x, seqlen, gsum, gsq);

    dim3 grid2(128, B);   // 2048 blocks, ~61 iters each
    pin_norm_kernel<<<grid2, block, 0, stream>>>(x, seqlen, gsum, gsq, weight, bias, out);
}